// Round 6
// baseline (880.447 us; speedup 1.0000x reference)
//
#include <hip/hip_runtime.h>

// LoRA linear, rank 16:  out = x @ (B@A)^T  ==  (x @ A^T) @ B^T
// x:[M=8192,4096] f32, A:[16,4096] f32, B:[4096,16] f32, out:[M,4096] f32.
// Mandatory HBM traffic: 128 MiB x-read + 128 MiB out-write -> ~42 us floor.
// R4 theory: out-stores and x-loads are zero-reuse streams -> nontemporal,
// so A and B stay L2-resident (R3: k2 FETCH 194 MiB = B evicted by store
// stream; WRITE 496 MiB = 3.9x amplification). k1 loads its whole x share
// up-front (32 KB/wave in flight) to kill load->FMA round-trip serialization.

#define INCH  4096
#define OUTCH 4096
#define RD    16

using f4 = float __attribute__((ext_vector_type(4)));

// ---------------------------------------------------------------- kernel 1
// grid = (M/16)*2 blocks of 256 threads; block = 16 rows x 2048 cols (K-half).
// Wave = 4 rows. All 8 chunks (32 f4 nt-loads/thread) issued before FMAs.
__global__ __launch_bounds__(256, 2)
void lora_xa_kernel(const float* __restrict__ X, const float* __restrict__ A,
                    float* __restrict__ Tp, int M) {
    __shared__ float scratch[4][64][20];

    const int tid  = threadIdx.x;
    const int w    = tid >> 6;
    const int lane = tid & 63;
    const int kb   = blockIdx.x & 1;     // K half
    const int rg   = blockIdx.x >> 1;
    const int row0 = rg * 16 + w * 4;

    const f4* A4 = reinterpret_cast<const f4*>(A);
    const f4* xp[4];
#pragma unroll
    for (int q = 0; q < 4; ++q)
        xp[q] = reinterpret_cast<const f4*>(
                    X + (size_t)(row0 + q) * INCH + kb * 2048) + lane;

    // Entire x share in flight: chunks 0-3 then 4-7 (nt: don't pollute L2).
    f4 xv[4][4], xw[4][4];
#pragma unroll
    for (int c = 0; c < 4; ++c)
#pragma unroll
        for (int q = 0; q < 4; ++q)
            xv[c][q] = __builtin_nontemporal_load(xp[q] + c * 64);
#pragma unroll
    for (int c = 0; c < 4; ++c)
#pragma unroll
        for (int q = 0; q < 4; ++q)
            xw[c][q] = __builtin_nontemporal_load(xp[q] + (c + 4) * 64);

    float acc[4][RD] = {};
    const int abase = kb * 512 + lane;   // f4 units within an A row
#pragma unroll
    for (int c = 0; c < 4; ++c) {
#pragma unroll
        for (int r = 0; r < RD; ++r) {
            f4 a4 = A4[(size_t)r * (INCH / 4) + abase + c * 64];
#pragma unroll
            for (int q = 0; q < 4; ++q)
                acc[q][r] += xv[c][q][0] * a4[0] + xv[c][q][1] * a4[1]
                           + xv[c][q][2] * a4[2] + xv[c][q][3] * a4[3];
        }
    }
#pragma unroll
    for (int c = 0; c < 4; ++c) {
#pragma unroll
        for (int r = 0; r < RD; ++r) {
            f4 a4 = A4[(size_t)r * (INCH / 4) + abase + (c + 4) * 64];
#pragma unroll
            for (int q = 0; q < 4; ++q)
                acc[q][r] += xw[c][q][0] * a4[0] + xw[c][q][1] * a4[1]
                           + xw[c][q][2] * a4[2] + xw[c][q][3] * a4[3];
        }
    }

    // Cross-lane reduce: per-wave LDS transpose (pad 20) + butterfly.
    const int s = lane >> 4, j = lane & 15;
    for (int q = 0; q < 4; ++q) {
#pragma unroll
        for (int k = 0; k < 4; ++k) {
            *reinterpret_cast<f4*>(&scratch[w][lane][k * 4]) =
                f4{acc[q][k * 4 + 0], acc[q][k * 4 + 1],
                   acc[q][k * 4 + 2], acc[q][k * 4 + 3]};
        }
        __syncthreads();
        float v = 0.f;
#pragma unroll
        for (int k = 0; k < 16; ++k) v += scratch[w][s * 16 + k][j];
        v += __shfl_xor(v, 16);
        v += __shfl_xor(v, 32);
        if (lane < 16)
            Tp[(size_t)kb * M * RD + (size_t)(row0 + q) * RD + lane] = v;
        __syncthreads();
    }
}

// ---------------------------------------------------------------- kernel 2
// grid = (M/16)*8 blocks of 256 threads; block = 16 rows x 512 outputs.
// B slice -> padded LDS (2-way=free writes); out via nontemporal f4 stores.
__global__ __launch_bounds__(256, 4)
void lora_tb_kernel(const float* __restrict__ Tp, const float* __restrict__ B,
                    float* __restrict__ OUT, int M) {
    __shared__ float bt[RD][516];        // pad 512->516: kills 4-way wr conflicts
    __shared__ float ts[16][RD];

    const int tid = threadIdx.x;
    const int og  = blockIdx.x & 7;
    const int rg  = blockIdx.x >> 3;
    const int o0  = og * 512;

    const f4* B4 = reinterpret_cast<const f4*>(B);
#pragma unroll
    for (int rep = 0; rep < 8; ++rep) {
        int t  = rep * 256 + tid;
        int ol = t >> 2, r4 = t & 3;
        f4 b4 = B4[(size_t)(o0 + ol) * 4 + r4];
        bt[r4 * 4 + 0][ol] = b4[0];
        bt[r4 * 4 + 1][ol] = b4[1];
        bt[r4 * 4 + 2][ol] = b4[2];
        bt[r4 * 4 + 3][ol] = b4[3];
    }
    {
        int row16 = tid >> 4, r = tid & 15;
        int row = rg * 16 + row16;
        ts[row16][r] = Tp[(size_t)row * RD + r]
                     + Tp[(size_t)(M + row) * RD + r];   // sum K-halves
    }
    __syncthreads();

    const int w = tid >> 6, lane = tid & 63;
    const int row0 = rg * 16 + w * 4;

    f4 oa[4], ob[4];
#pragma unroll
    for (int q = 0; q < 4; ++q) { oa[q] = (f4)0.f; ob[q] = (f4)0.f; }

#pragma unroll
    for (int r = 0; r < RD; ++r) {
        f4 ba = *reinterpret_cast<const f4*>(&bt[r][lane * 4]);
        f4 bb = *reinterpret_cast<const f4*>(&bt[r][256 + lane * 4]);
#pragma unroll
        for (int q = 0; q < 4; ++q) {
            float t = ts[w * 4 + q][r];  // wave-uniform LDS broadcast
            oa[q] += t * ba;
            ob[q] += t * bb;
        }
    }

#pragma unroll
    for (int q = 0; q < 4; ++q) {
        float* base = OUT + (size_t)(row0 + q) * OUTCH + o0;
        __builtin_nontemporal_store(oa[q],
            reinterpret_cast<f4*>(base) + lane);
        __builtin_nontemporal_store(ob[q],
            reinterpret_cast<f4*>(base + 256) + lane);
    }
}

extern "C" void kernel_launch(void* const* d_in, const int* in_sizes, int n_in,
                              void* d_out, int out_size, void* d_ws, size_t ws_size,
                              hipStream_t stream) {
    const float* X  = (const float*)d_in[0];   // [M, 4096]
    const float* A  = (const float*)d_in[1];   // [16, 4096]
    const float* Bm = (const float*)d_in[2];   // [4096, 16]
    float*       O  = (float*)d_out;           // [M, 4096]
    float*       Tp = (float*)d_ws;            // [2][M][16] = 1 MB partials

    const int M = in_sizes[0] / INCH;          // 8192

    hipLaunchKernelGGL(lora_xa_kernel, dim3((M / 16) * 2), dim3(256), 0, stream,
                       X, A, Tp, M);
    hipLaunchKernelGGL(lora_tb_kernel, dim3((M / 16) * 8), dim3(256), 0, stream,
                       Tp, Bm, O, M);
}

// Round 9
// 261.069 us; speedup vs baseline: 3.3725x; 3.3725x over previous
//
#include <hip/hip_runtime.h>

// LoRA linear, rank 16:  out = x @ (B@A)^T  ==  (x @ A^T) @ B^T
// x:[M=8192,4096] f32, A:[16,4096] f32, B:[4096,16] f32, out:[M,4096] f32.
// Mandatory HBM traffic: 128 MiB x-read + 128 MiB out-write -> ~42 us floor.
// R7: k1 = R3's proven 2-deep-prefetch structure (R6's 32-f4 upfront batch
// spilled to scratch: VGPR capped 128, FETCH 892 MiB, 707 us) + nt x-loads
// + scratch pad 17 (2-way=free). k2 = nt stores + 516 pad, unmeasured in R6.

#define INCH  4096
#define OUTCH 4096
#define RD    16

using f4 = float __attribute__((ext_vector_type(4)));

// ---------------------------------------------------------------- kernel 1
// grid = (M/16)*2 blocks of 256 threads; block = 16 rows x 2048 cols (K-half).
// Wave = 4 rows; lane covers cols (chunk*256 + lane*4): coalesced f4 nt-loads.
// 2-deep x prefetch (8 f4 live = 32 VGPR; acc 64; total ~128, no spill).
__global__ __launch_bounds__(256, 3)
void lora_xa_kernel(const float* __restrict__ X, const float* __restrict__ A,
                    float* __restrict__ Tp, int M) {
    __shared__ float scratch[4][64][17];   // pad 17: write 2-way, read 2-way (free)

    const int tid  = threadIdx.x;
    const int w    = tid >> 6;
    const int lane = tid & 63;
    const int kb   = blockIdx.x & 1;       // K half
    const int rg   = blockIdx.x >> 1;
    const int row0 = rg * 16 + w * 4;

    const f4* A4 = reinterpret_cast<const f4*>(A);

    float acc[4][RD] = {};

    const f4* xp[4];
#pragma unroll
    for (int q = 0; q < 4; ++q)
        xp[q] = reinterpret_cast<const f4*>(
                    X + (size_t)(row0 + q) * INCH + kb * 2048) + lane;

    f4 xc[4], xn[4];
#pragma unroll
    for (int q = 0; q < 4; ++q) xc[q] = __builtin_nontemporal_load(xp[q]);

    const int abase = kb * 512 + lane;     // f4 units within an A row
    for (int c = 0; c < 8; ++c) {          // 8 chunks x 256 cols
        if (c < 7) {
#pragma unroll
            for (int q = 0; q < 4; ++q)
                xn[q] = __builtin_nontemporal_load(xp[q] + (c + 1) * 64);
        }
#pragma unroll
        for (int r = 0; r < RD; ++r) {
            f4 a4 = A4[(size_t)r * (INCH / 4) + abase + c * 64];
#pragma unroll
            for (int q = 0; q < 4; ++q)
                acc[q][r] += xc[q][0] * a4[0] + xc[q][1] * a4[1]
                           + xc[q][2] * a4[2] + xc[q][3] * a4[3];
        }
        if (c < 7) {
#pragma unroll
            for (int q = 0; q < 4; ++q) xc[q] = xn[q];
        }
    }

    // Cross-lane reduce: per-wave LDS transpose + butterfly.
    const int s = lane >> 4, j = lane & 15;
    for (int q = 0; q < 4; ++q) {
#pragma unroll
        for (int k = 0; k < 4; ++k) {
            *reinterpret_cast<f4*>(&scratch[w][lane][k * 4]) =
                f4{acc[q][k * 4 + 0], acc[q][k * 4 + 1],
                   acc[q][k * 4 + 2], acc[q][k * 4 + 3]};
        }
        __syncthreads();
        float v = 0.f;
#pragma unroll
        for (int k = 0; k < 16; ++k) v += scratch[w][s * 16 + k][j];
        v += __shfl_xor(v, 16);
        v += __shfl_xor(v, 32);
        if (lane < 16)
            Tp[(size_t)kb * M * RD + (size_t)(row0 + q) * RD + lane] = v;
        __syncthreads();
    }
}

// ---------------------------------------------------------------- kernel 2
// grid = (M/16)*8 blocks of 256 threads; block = 16 rows x 512 outputs.
// B slice -> padded LDS; out via nontemporal f4 stores (keep L2 for B/Tp).
__global__ __launch_bounds__(256, 4)
void lora_tb_kernel(const float* __restrict__ Tp, const float* __restrict__ B,
                    float* __restrict__ OUT, int M) {
    __shared__ float bt[RD][516];        // pad 512->516: kills 4-way wr conflicts
    __shared__ float ts[16][RD];

    const int tid = threadIdx.x;
    const int og  = blockIdx.x & 7;
    const int rg  = blockIdx.x >> 3;
    const int o0  = og * 512;

    const f4* B4 = reinterpret_cast<const f4*>(B);
#pragma unroll
    for (int rep = 0; rep < 8; ++rep) {
        int t  = rep * 256 + tid;
        int ol = t >> 2, r4 = t & 3;
        f4 b4 = B4[(size_t)(o0 + ol) * 4 + r4];
        bt[r4 * 4 + 0][ol] = b4[0];
        bt[r4 * 4 + 1][ol] = b4[1];
        bt[r4 * 4 + 2][ol] = b4[2];
        bt[r4 * 4 + 3][ol] = b4[3];
    }
    {
        int row16 = tid >> 4, r = tid & 15;
        int row = rg * 16 + row16;
        ts[row16][r] = Tp[(size_t)row * RD + r]
                     + Tp[(size_t)(M + row) * RD + r];   // sum K-halves
    }
    __syncthreads();

    const int w = tid >> 6, lane = tid & 63;
    const int row0 = rg * 16 + w * 4;

    f4 oa[4], ob[4];
#pragma unroll
    for (int q = 0; q < 4; ++q) { oa[q] = (f4)0.f; ob[q] = (f4)0.f; }

#pragma unroll
    for (int r = 0; r < RD; ++r) {
        f4 ba = *reinterpret_cast<const f4*>(&bt[r][lane * 4]);
        f4 bb = *reinterpret_cast<const f4*>(&bt[r][256 + lane * 4]);
#pragma unroll
        for (int q = 0; q < 4; ++q) {
            float t = ts[w * 4 + q][r];  // wave-uniform LDS broadcast
            oa[q] += t * ba;
            ob[q] += t * bb;
        }
    }

#pragma unroll
    for (int q = 0; q < 4; ++q) {
        float* base = OUT + (size_t)(row0 + q) * OUTCH + o0;
        __builtin_nontemporal_store(oa[q], reinterpret_cast<f4*>(base) + lane);
        __builtin_nontemporal_store(ob[q],
            reinterpret_cast<f4*>(base + 256) + lane);
    }
}

extern "C" void kernel_launch(void* const* d_in, const int* in_sizes, int n_in,
                              void* d_out, int out_size, void* d_ws, size_t ws_size,
                              hipStream_t stream) {
    const float* X  = (const float*)d_in[0];   // [M, 4096]
    const float* A  = (const float*)d_in[1];   // [16, 4096]
    const float* Bm = (const float*)d_in[2];   // [4096, 16]
    float*       O  = (float*)d_out;           // [M, 4096]
    float*       Tp = (float*)d_ws;            // [2][M][16] = 1 MB partials

    const int M = in_sizes[0] / INCH;          // 8192

    hipLaunchKernelGGL(lora_xa_kernel, dim3((M / 16) * 2), dim3(256), 0, stream,
                       X, A, Tp, M);
    hipLaunchKernelGGL(lora_tb_kernel, dim3((M / 16) * 8), dim3(256), 0, stream,
                       Tp, Bm, O, M);
}